// Round 2
// baseline (1682.926 us; speedup 1.0000x reference)
//
#include <hip/hip_runtime.h>
#include <hip/hip_bf16.h>
#include <cstdint>
#include <cstddef>

// ---------------- problem constants ----------------
#define B_    8
#define S_    1500
#define D_    1024
#define H_    16
#define HD_   64
#define DFF_  4096
#define M_    12000   // B_*S_
#define VTS_  1536    // padded seq stride for V^T

typedef __bf16 bf16;
typedef __attribute__((ext_vector_type(8))) __bf16 bf16x8;
typedef __attribute__((ext_vector_type(4))) float f32x4;

#define MFMA16(a, b, c) __builtin_amdgcn_mfma_f32_16x16x32_bf16((a), (b), (c), 0, 0, 0)

// async global->LDS, 16B per lane (wave-uniform base + lane*16 dest).
static __device__ __forceinline__ void gload16(const void* g, void* l) {
  __builtin_amdgcn_global_load_lds(
      (const __attribute__((address_space(1))) void*)(uintptr_t)g,
      (__attribute__((address_space(3))) void*)(uintptr_t)l, 16, 0, 0);
}

static __device__ __forceinline__ unsigned short f2bu(float v) {
  bf16 h = (bf16)v;
  union { bf16 h; unsigned short u; } c;
  c.h = h;
  return c.u;
}

// ---------------- workspace layout (bytes) ----------------
static constexpr size_t WQ_OFF  = 0;
static constexpr size_t WK_OFF  = WQ_OFF + (size_t)D_ * D_ * 2;
static constexpr size_t WV_OFF  = WK_OFF + (size_t)D_ * D_ * 2;
static constexpr size_t WO_OFF  = WV_OFF + (size_t)D_ * D_ * 2;
static constexpr size_t W1_OFF  = WO_OFF + (size_t)D_ * D_ * 2;
static constexpr size_t W2_OFF  = W1_OFF + (size_t)DFF_ * D_ * 2;
static constexpr size_t H_OFF   = W2_OFF + (size_t)DFF_ * D_ * 2;   // h -> ctx -> act-chunk
static constexpr size_t HSZ     = (size_t)M_ * D_ * 2;              // 24,576,000
static constexpr size_t Q_OFF   = H_OFF + HSZ;
static constexpr size_t K_OFF   = Q_OFF + HSZ;
static constexpr size_t VT_OFF  = K_OFF + HSZ;                      // V^T [128][64][1536] bf16
static constexpr size_t X2_OFF  = Q_OFF;   // fp32 x2 overlays q+k (exactly 2*HSZ)
static constexpr size_t H2_OFF  = VT_OFF;  // h2 overlays vt (vt dead after attn)
static constexpr size_t ACT_OFF = H_OFF;   // act chunk overlays h/ctx

// ---------------- fp32 -> bf16 convert ----------------
__launch_bounds__(256)
__global__ void cvt_bf16(const float* __restrict__ src, bf16* __restrict__ dst, int n) {
  int i = (blockIdx.x * 256 + threadIdx.x) * 4;
  if (i < n) {
    float4 f = *(const float4*)(src + i);
    dst[i + 0] = (bf16)f.x;
    dst[i + 1] = (bf16)f.y;
    dst[i + 2] = (bf16)f.z;
    dst[i + 3] = (bf16)f.w;
  }
}

// ---------------- fused LayerNorm (fp32 in, bf16 out), one block per row ----------------
__launch_bounds__(256)
__global__ void ln_fused(const float* __restrict__ x, const float* __restrict__ g,
                         const float* __restrict__ bb, bf16* __restrict__ out) {
  const int row = blockIdx.x;
  const int t = threadIdx.x;
  const float4 xv = *(const float4*)(x + (size_t)row * D_ + t * 4);
  float s  = xv.x + xv.y + xv.z + xv.w;
  float s2 = xv.x * xv.x + xv.y * xv.y + xv.z * xv.z + xv.w * xv.w;
#pragma unroll
  for (int m = 32; m >= 1; m >>= 1) {
    s  += __shfl_xor(s, m);
    s2 += __shfl_xor(s2, m);
  }
  __shared__ float red[8];
  const int w = t >> 6;
  if ((t & 63) == 0) { red[w] = s; red[4 + w] = s2; }
  __syncthreads();
  s  = red[0] + red[1] + red[2] + red[3];
  s2 = red[4] + red[5] + red[6] + red[7];
  const float mu  = s * (1.0f / D_);
  const float var = s2 * (1.0f / D_) - mu * mu;
  const float rs  = rsqrtf(var + 1e-5f);
  const float4 gv = *(const float4*)(g + t * 4);
  const float4 bv = *(const float4*)(bb + t * 4);
  bf16* o = out + (size_t)row * D_ + t * 4;
  o[0] = (bf16)((xv.x - mu) * rs * gv.x + bv.x);
  o[1] = (bf16)((xv.y - mu) * rs * gv.y + bv.y);
  o[2] = (bf16)((xv.z - mu) * rs * gv.z + bv.z);
  o[3] = (bf16)((xv.w - mu) * rs * gv.w + bv.w);
}

// ---------------- GEMM: C[m][n] = sum_k A[m][k] * W[n][k]  (both K-contiguous) ----------------
// 128x128 tile, BK=64, 256 threads (4 waves, 2x2), 16x16x32 bf16 MFMA (m97 structure).
// EPI: 0 = store bf16; 1 = store bf16 * scale; 2 = bias + exact GELU -> bf16;
//      3 = (+bias) + resid -> fp32; 4 = store transposed V^T bf16 (outB = vt base)
template <int EPI>
__launch_bounds__(256)
__global__ void gemm_bt(const bf16* __restrict__ A, const bf16* __restrict__ Bw,
                        int M, int N, int K,
                        bf16* __restrict__ outB, float* __restrict__ outF,
                        const float* __restrict__ bias, const float* __restrict__ resid,
                        float scale) {
  __shared__ bf16 a_lds[128 * 64];
  __shared__ bf16 b_lds[128 * 64];
  const int t = threadIdx.x;
  const int lane = t & 63, wid = t >> 6;
  const int wr = wid >> 1, wc = wid & 1;
  const int mrow0 = blockIdx.x * 128;
  const int ncol0 = blockIdx.y * 128;
  const int l15 = lane & 15;
  const int khi = (lane >> 4) << 3;

  f32x4 acc[4][4] = {};

  for (int k0 = 0; k0 < K; k0 += 64) {
#pragma unroll
    for (int i = 0; i < 4; ++i) {  // A tile 128x64
      int idx = i * 2048 + t * 8;
      int row = idx >> 6, col = idx & 63;
      int gr = mrow0 + row;
      gr = gr < M ? gr : M - 1;
      gload16(A + (size_t)gr * K + (k0 + col), (char*)a_lds + idx * 2);
    }
#pragma unroll
    for (int i = 0; i < 4; ++i) {  // B tile 128x64 (N always multiple of 128)
      int idx = i * 2048 + t * 8;
      int row = idx >> 6, col = idx & 63;
      gload16(Bw + (size_t)(ncol0 + row) * K + (k0 + col), (char*)b_lds + idx * 2);
    }
    __syncthreads();
#pragma unroll
    for (int kk = 0; kk < 2; ++kk) {
      bf16x8 af[4], bfv[4];
#pragma unroll
      for (int m = 0; m < 4; ++m)
        af[m] = *(const bf16x8*)&a_lds[(wr * 64 + m * 16 + l15) * 64 + kk * 32 + khi];
#pragma unroll
      for (int n = 0; n < 4; ++n)
        bfv[n] = *(const bf16x8*)&b_lds[(wc * 64 + n * 16 + l15) * 64 + kk * 32 + khi];
#pragma unroll
      for (int m = 0; m < 4; ++m)
#pragma unroll
        for (int n = 0; n < 4; ++n)
          acc[m][n] = MFMA16(af[m], bfv[n], acc[m][n]);
    }
    __syncthreads();
  }

  const int r0 = (lane >> 4) << 2;

  if constexpr (EPI == 4) {
    // transposed store: vt[(b*16 + f/64)*64 + f%64][s], row stride VTS_.
    // each lane holds 4 consecutive seq rows per (m,n); 1500 % 4 == 0 so a
    // 4-row group never straddles a batch boundary -> single 8B store.
#pragma unroll
    for (int m = 0; m < 4; ++m) {
      int row0 = mrow0 + wr * 64 + m * 16 + r0;
      if (row0 < M) {
        int bb2 = row0 / 1500;
        int s = row0 - bb2 * 1500;
#pragma unroll
        for (int n = 0; n < 4; ++n) {
          int f = ncol0 + wc * 64 + n * 16 + l15;
          size_t a = ((size_t)(bb2 * 16 + (f >> 6)) * 64 + (f & 63)) * VTS_ + s;
          ushort4 pk;
          pk.x = f2bu(acc[m][n][0]);
          pk.y = f2bu(acc[m][n][1]);
          pk.z = f2bu(acc[m][n][2]);
          pk.w = f2bu(acc[m][n][3]);
          *reinterpret_cast<ushort4*>((unsigned short*)outB + a) = pk;
        }
      }
    }
    return;
  }

#pragma unroll
  for (int m = 0; m < 4; ++m) {
#pragma unroll
    for (int n = 0; n < 4; ++n) {
      int col = ncol0 + wc * 64 + n * 16 + l15;
#pragma unroll
      for (int r = 0; r < 4; ++r) {
        int row = mrow0 + wr * 64 + m * 16 + r0 + r;
        if (row < M) {
          float v = acc[m][n][r];
          if constexpr (EPI == 1) v *= scale;
          if constexpr (EPI == 2) {
            float xg = v + bias[col];
            v = 0.5f * xg * (1.0f + erff(xg * 0.70710678118654752f));
          }
          if constexpr (EPI == 3) {
            v += resid[(size_t)row * N + col];
            if (bias) v += bias[col];
            outF[(size_t)row * N + col] = v;
          } else {
            outB[(size_t)row * N + col] = (bf16)v;
          }
        }
      }
    }
  }
}

// ---------------- flash attention fwd v2: K and V^T direct from global ----------------
// grid: (ceil(S/64), B*H); block 256 = 4 waves; wave w owns 16 q-rows.
// No __syncthreads in the K-loop; only P transits (per-wave, swizzled) LDS.
__launch_bounds__(256)
__global__ void attn_fwd2(const bf16* __restrict__ q, const bf16* __restrict__ kg,
                          const bf16* __restrict__ vt, bf16* __restrict__ cx) {
  __shared__ bf16 p_lds[4][16 * 72];

  const int t = threadIdx.x;
  const int lane = t & 63, w = t >> 6;
  const int qt = blockIdx.x;
  const int bh = blockIdx.y;
  const int l15 = lane & 15;
  const int hi = lane >> 4;
  const int khi = hi << 3;

  const size_t hoff = ((size_t)(bh >> 4) * S_) * D_ + (size_t)(bh & 15) * HD_;
  const bf16* qh = q + hoff;
  const bf16* kh = kg + hoff;
  const bf16* vh = vt + (size_t)bh * (64 * VTS_);

  int qr = qt * 64 + w * 16 + l15;
  int qrc = qr < S_ ? qr : S_ - 1;
  const bf16x8 qf0 = *(const bf16x8*)(qh + (size_t)qrc * D_ + khi);
  const bf16x8 qf1 = *(const bf16x8*)(qh + (size_t)qrc * D_ + 32 + khi);

  f32x4 oacc[4] = {};
  float mrun[4], lrun[4];
#pragma unroll
  for (int r = 0; r < 4; ++r) { mrun[r] = -1e30f; lrun[r] = 0.f; }

  bf16* pw = &p_lds[w][0];
  const int NT = (S_ + 63) / 64;  // 24

  for (int kt = 0; kt < NT; ++kt) {
    // ---- S = Q K^T, K fragments straight from global (L1/L2-served) ----
    float pv[4][4];
#pragma unroll
    for (int nb = 0; nb < 4; ++nb) {
      int key = kt * 64 + nb * 16 + l15;
      int keyc = key < S_ ? key : S_ - 1;
      const bf16* kp = kh + (size_t)keyc * D_;
      f32x4 z = {};
      z = MFMA16(qf0, *(const bf16x8*)(kp + khi), z);
      z = MFMA16(qf1, *(const bf16x8*)(kp + 32 + khi), z);
      bool cvld = key < S_;
#pragma unroll
      for (int r = 0; r < 4; ++r) pv[nb][r] = cvld ? z[r] : -1e30f;
    }

    // ---- online softmax (rows r: hi*4+r, cols: nb*16 + l15) ----
#pragma unroll
    for (int r = 0; r < 4; ++r) {
      float mx = fmaxf(fmaxf(pv[0][r], pv[1][r]), fmaxf(pv[2][r], pv[3][r]));
      mx = fmaxf(mx, __shfl_xor(mx, 1));
      mx = fmaxf(mx, __shfl_xor(mx, 2));
      mx = fmaxf(mx, __shfl_xor(mx, 4));
      mx = fmaxf(mx, __shfl_xor(mx, 8));
      float mnew = fmaxf(mrun[r], mx);
      float corr = __expf(mrun[r] - mnew);
      float ps = 0.f;
#pragma unroll
      for (int nb = 0; nb < 4; ++nb) {
        float p = __expf(pv[nb][r] - mnew);
        pv[nb][r] = p;
        ps += p;
      }
      ps += __shfl_xor(ps, 1);
      ps += __shfl_xor(ps, 2);
      ps += __shfl_xor(ps, 4);
      ps += __shfl_xor(ps, 8);
      lrun[r] = lrun[r] * corr + ps;
      mrun[r] = mnew;
#pragma unroll
      for (int db = 0; db < 4; ++db) oacc[db][r] *= corr;
    }

    // ---- P -> per-wave LDS (stride 72, XOR-swizzled chunks) ----
#pragma unroll
    for (int nb = 0; nb < 4; ++nb) {
#pragma unroll
      for (int r = 0; r < 4; ++r) {
        int prow = hi * 4 + r;
        int pcol = (nb * 16 + l15) ^ ((prow & 7) << 3);
        pw[prow * 72 + pcol] = (bf16)pv[nb][r];
      }
    }

    // ---- ctx += P @ V, V^T fragments straight from global ----
    const bf16* vb = vh + kt * 64;
#pragma unroll
    for (int kk = 0; kk < 2; ++kk) {
      bf16x8 pf = *(const bf16x8*)&pw[l15 * 72 + ((kk * 32 + khi) ^ ((l15 & 7) << 3))];
#pragma unroll
      for (int db = 0; db < 4; ++db) {
        bf16x8 vf = *(const bf16x8*)(vb + (size_t)(db * 16 + l15) * VTS_ + kk * 32 + khi);
        oacc[db] = MFMA16(pf, vf, oacc[db]);
      }
    }
  }

  // ---- normalize + store ----
#pragma unroll
  for (int r = 0; r < 4; ++r) {
    int qrow = qt * 64 + w * 16 + hi * 4 + r;
    if (qrow < S_) {
      float inv = 1.0f / lrun[r];
#pragma unroll
      for (int db = 0; db < 4; ++db)
        cx[hoff + (size_t)qrow * D_ + db * 16 + l15] = (bf16)(oacc[db][r] * inv);
    }
  }
}

// ---------------- launch ----------------
extern "C" void kernel_launch(void* const* d_in, const int* in_sizes, int n_in,
                              void* d_out, int out_size, void* d_ws, size_t ws_size,
                              hipStream_t stream) {
  const float* x   = (const float*)d_in[0];
  const float* Wq  = (const float*)d_in[1];
  const float* Wk  = (const float*)d_in[2];
  const float* Wv  = (const float*)d_in[3];
  const float* Wo  = (const float*)d_in[4];
  const float* W1  = (const float*)d_in[5];
  const float* b1  = (const float*)d_in[6];
  const float* W2  = (const float*)d_in[7];
  const float* b2  = (const float*)d_in[8];
  const float* g1  = (const float*)d_in[9];
  const float* be1 = (const float*)d_in[10];
  const float* g2  = (const float*)d_in[11];
  const float* be2 = (const float*)d_in[12];
  float* out = (float*)d_out;

  char* ws = (char*)d_ws;
  bf16* wq_b  = (bf16*)(ws + WQ_OFF);
  bf16* wk_b  = (bf16*)(ws + WK_OFF);
  bf16* wv_b  = (bf16*)(ws + WV_OFF);
  bf16* wo_b  = (bf16*)(ws + WO_OFF);
  bf16* w1_b  = (bf16*)(ws + W1_OFF);
  bf16* w2_b  = (bf16*)(ws + W2_OFF);
  bf16* h_b   = (bf16*)(ws + H_OFF);
  bf16* q_b   = (bf16*)(ws + Q_OFF);
  bf16* k_b   = (bf16*)(ws + K_OFF);
  bf16* vt_b  = (bf16*)(ws + VT_OFF);
  float* x2   = (float*)(ws + X2_OFF);
  bf16* h2_b  = (bf16*)(ws + H2_OFF);
  bf16* act_b = (bf16*)(ws + ACT_OFF);
  bf16* ctx_b = h_b;  // ctx overlays h

  // weight converts
  cvt_bf16<<<(D_ * D_) / 1024, 256, 0, stream>>>(Wq, wq_b, D_ * D_);
  cvt_bf16<<<(D_ * D_) / 1024, 256, 0, stream>>>(Wk, wk_b, D_ * D_);
  cvt_bf16<<<(D_ * D_) / 1024, 256, 0, stream>>>(Wv, wv_b, D_ * D_);
  cvt_bf16<<<(D_ * D_) / 1024, 256, 0, stream>>>(Wo, wo_b, D_ * D_);
  cvt_bf16<<<(DFF_ * D_) / 1024, 256, 0, stream>>>(W1, w1_b, DFF_ * D_);
  cvt_bf16<<<(DFF_ * D_) / 1024, 256, 0, stream>>>(W2, w2_b, DFF_ * D_);

  // LN1
  ln_fused<<<M_, 256, 0, stream>>>(x, g1, be1, h_b);

  // QKV projections (V writes transposed V^T directly)
  dim3 gqkv((M_ + 127) / 128, D_ / 128);
  gemm_bt<1><<<gqkv, 256, 0, stream>>>(h_b, wq_b, M_, D_, D_, q_b, nullptr, nullptr, nullptr, 0.125f);
  gemm_bt<0><<<gqkv, 256, 0, stream>>>(h_b, wk_b, M_, D_, D_, k_b, nullptr, nullptr, nullptr, 0.f);
  gemm_bt<4><<<gqkv, 256, 0, stream>>>(h_b, wv_b, M_, D_, D_, vt_b, nullptr, nullptr, nullptr, 0.f);

  // attention (writes ctx into h region; h dead after QKV)
  attn_fwd2<<<dim3((S_ + 63) / 64, B_ * H_), 256, 0, stream>>>(q_b, k_b, vt_b, ctx_b);

  // x2 = x + ctx @ Wo^T   (x2 overlays q+k; q/k dead)
  gemm_bt<3><<<gqkv, 256, 0, stream>>>(ctx_b, wo_b, M_, D_, D_, nullptr, x2, nullptr, x, 0.f);

  // LN2 (h2 overlays vt; vt dead)
  ln_fused<<<M_, 256, 0, stream>>>(x2, g2, be2, h2_b);

  // FFN in 5 row-chunks of 2400 (act chunk overlays h/ctx; ctx dead)
  for (int c = 0; c < 5; ++c) {
    int r0c = c * 2400;
    int nr = 2400;
    int mt = (nr + 127) / 128;
    gemm_bt<2><<<dim3(mt, DFF_ / 128), 256, 0, stream>>>(
        h2_b + (size_t)r0c * D_, w1_b, nr, DFF_, D_, act_b, nullptr, b1, nullptr, 0.f);
    gemm_bt<3><<<dim3(mt, D_ / 128), 256, 0, stream>>>(
        act_b, w2_b, nr, D_, DFF_, nullptr, out + (size_t)r0c * D_, b2,
        x2 + (size_t)r0c * D_, 0.f);
  }
}

// Round 3
// 1410.113 us; speedup vs baseline: 1.1935x; 1.1935x over previous
//
#include <hip/hip_runtime.h>
#include <hip/hip_bf16.h>
#include <cstdint>
#include <cstddef>

// ---------------- problem constants ----------------
#define B_    8
#define S_    1500
#define D_    1024
#define H_    16
#define HD_   64
#define DFF_  4096
#define M_    12000   // B_*S_
#define VTS_  1536    // padded seq stride for V^T

typedef __bf16 bf16;
typedef __attribute__((ext_vector_type(8))) __bf16 bf16x8;
typedef __attribute__((ext_vector_type(4))) float f32x4;

#define MFMA16(a, b, c) __builtin_amdgcn_mfma_f32_16x16x32_bf16((a), (b), (c), 0, 0, 0)

// async global->LDS, 16B per lane (wave-uniform base + lane*16 dest).
static __device__ __forceinline__ void gload16(const void* g, void* l) {
  __builtin_amdgcn_global_load_lds(
      (const __attribute__((address_space(1))) void*)(uintptr_t)g,
      (__attribute__((address_space(3))) void*)(uintptr_t)l, 16, 0, 0);
}

static __device__ __forceinline__ unsigned short f2bu(float v) {
  bf16 h = (bf16)v;
  union { bf16 h; unsigned short u; } c;
  c.h = h;
  return c.u;
}

// ---------------- workspace layout (bytes) ----------------
static constexpr size_t WQ_OFF  = 0;
static constexpr size_t WK_OFF  = WQ_OFF + (size_t)D_ * D_ * 2;
static constexpr size_t WV_OFF  = WK_OFF + (size_t)D_ * D_ * 2;
static constexpr size_t WO_OFF  = WV_OFF + (size_t)D_ * D_ * 2;
static constexpr size_t W1_OFF  = WO_OFF + (size_t)D_ * D_ * 2;
static constexpr size_t W2_OFF  = W1_OFF + (size_t)DFF_ * D_ * 2;
static constexpr size_t H_OFF   = W2_OFF + (size_t)DFF_ * D_ * 2;   // h -> ctx -> act-chunk
static constexpr size_t HSZ     = (size_t)M_ * D_ * 2;              // 24,576,000
static constexpr size_t Q_OFF   = H_OFF + HSZ;
static constexpr size_t K_OFF   = Q_OFF + HSZ;
static constexpr size_t VT_OFF  = K_OFF + HSZ;                      // V^T [128][64][1536] bf16
static constexpr size_t X2_OFF  = Q_OFF;   // fp32 x2 overlays q+k (exactly 2*HSZ)
static constexpr size_t H2_OFF  = VT_OFF;  // h2 overlays vt (vt dead after attn)
static constexpr size_t ACT_OFF = H_OFF;   // act chunk overlays h/ctx

// ---------------- fp32 -> bf16 convert ----------------
__launch_bounds__(256)
__global__ void cvt_bf16(const float* __restrict__ src, bf16* __restrict__ dst, int n) {
  int i = (blockIdx.x * 256 + threadIdx.x) * 4;
  if (i < n) {
    float4 f = *(const float4*)(src + i);
    dst[i + 0] = (bf16)f.x;
    dst[i + 1] = (bf16)f.y;
    dst[i + 2] = (bf16)f.z;
    dst[i + 3] = (bf16)f.w;
  }
}

// ---------------- fused LayerNorm (fp32 in, bf16 out), one block per row ----------------
__launch_bounds__(256)
__global__ void ln_fused(const float* __restrict__ x, const float* __restrict__ g,
                         const float* __restrict__ bb, bf16* __restrict__ out) {
  const int row = blockIdx.x;
  const int t = threadIdx.x;
  const float4 xv = *(const float4*)(x + (size_t)row * D_ + t * 4);
  float s  = xv.x + xv.y + xv.z + xv.w;
  float s2 = xv.x * xv.x + xv.y * xv.y + xv.z * xv.z + xv.w * xv.w;
#pragma unroll
  for (int m = 32; m >= 1; m >>= 1) {
    s  += __shfl_xor(s, m);
    s2 += __shfl_xor(s2, m);
  }
  __shared__ float red[8];
  const int w = t >> 6;
  if ((t & 63) == 0) { red[w] = s; red[4 + w] = s2; }
  __syncthreads();
  s  = red[0] + red[1] + red[2] + red[3];
  s2 = red[4] + red[5] + red[6] + red[7];
  const float mu  = s * (1.0f / D_);
  const float var = s2 * (1.0f / D_) - mu * mu;
  const float rs  = rsqrtf(var + 1e-5f);
  const float4 gv = *(const float4*)(g + t * 4);
  const float4 bv = *(const float4*)(bb + t * 4);
  bf16* o = out + (size_t)row * D_ + t * 4;
  o[0] = (bf16)((xv.x - mu) * rs * gv.x + bv.x);
  o[1] = (bf16)((xv.y - mu) * rs * gv.y + bv.y);
  o[2] = (bf16)((xv.z - mu) * rs * gv.z + bv.z);
  o[3] = (bf16)((xv.w - mu) * rs * gv.w + bv.w);
}

// ---------------- GEMM: C[m][n] = sum_k A[m][k] * W[n][k]  (both K-contiguous) ----------------
// 128x128 tile, BK=64, 256 threads (4 waves, 2x2), 16x16x32 bf16 MFMA (m97 structure).
// EPI: 0 = store bf16; 1 = store bf16 * scale; 2 = bias + exact GELU -> bf16;
//      3 = (+bias) + resid -> fp32; 4 = store transposed V^T bf16 (outB = vt base)
template <int EPI>
__launch_bounds__(256)
__global__ void gemm_bt(const bf16* __restrict__ A, const bf16* __restrict__ Bw,
                        int M, int N, int K,
                        bf16* __restrict__ outB, float* __restrict__ outF,
                        const float* __restrict__ bias, const float* __restrict__ resid,
                        float scale) {
  __shared__ bf16 a_lds[128 * 64];
  __shared__ bf16 b_lds[128 * 64];
  const int t = threadIdx.x;
  const int lane = t & 63, wid = t >> 6;
  const int wr = wid >> 1, wc = wid & 1;
  const int mrow0 = blockIdx.x * 128;
  const int ncol0 = blockIdx.y * 128;
  const int l15 = lane & 15;
  const int khi = (lane >> 4) << 3;

  f32x4 acc[4][4] = {};

  for (int k0 = 0; k0 < K; k0 += 64) {
#pragma unroll
    for (int i = 0; i < 4; ++i) {  // A tile 128x64
      int idx = i * 2048 + t * 8;
      int row = idx >> 6, col = idx & 63;
      int gr = mrow0 + row;
      gr = gr < M ? gr : M - 1;
      gload16(A + (size_t)gr * K + (k0 + col), (char*)a_lds + idx * 2);
    }
#pragma unroll
    for (int i = 0; i < 4; ++i) {  // B tile 128x64 (N always multiple of 128)
      int idx = i * 2048 + t * 8;
      int row = idx >> 6, col = idx & 63;
      gload16(Bw + (size_t)(ncol0 + row) * K + (k0 + col), (char*)b_lds + idx * 2);
    }
    __syncthreads();
#pragma unroll
    for (int kk = 0; kk < 2; ++kk) {
      bf16x8 af[4], bfv[4];
#pragma unroll
      for (int m = 0; m < 4; ++m)
        af[m] = *(const bf16x8*)&a_lds[(wr * 64 + m * 16 + l15) * 64 + kk * 32 + khi];
#pragma unroll
      for (int n = 0; n < 4; ++n)
        bfv[n] = *(const bf16x8*)&b_lds[(wc * 64 + n * 16 + l15) * 64 + kk * 32 + khi];
#pragma unroll
      for (int m = 0; m < 4; ++m)
#pragma unroll
        for (int n = 0; n < 4; ++n)
          acc[m][n] = MFMA16(af[m], bfv[n], acc[m][n]);
    }
    __syncthreads();
  }

  const int r0 = (lane >> 4) << 2;

  if constexpr (EPI == 4) {
    // transposed store: vt[(b*16 + f/64)*64 + f%64][s], row stride VTS_.
#pragma unroll
    for (int m = 0; m < 4; ++m) {
      int row0 = mrow0 + wr * 64 + m * 16 + r0;
      if (row0 < M) {
        int bb2 = row0 / 1500;
        int s = row0 - bb2 * 1500;
#pragma unroll
        for (int n = 0; n < 4; ++n) {
          int f = ncol0 + wc * 64 + n * 16 + l15;
          size_t a = ((size_t)(bb2 * 16 + (f >> 6)) * 64 + (f & 63)) * VTS_ + s;
          ushort4 pk;
          pk.x = f2bu(acc[m][n][0]);
          pk.y = f2bu(acc[m][n][1]);
          pk.z = f2bu(acc[m][n][2]);
          pk.w = f2bu(acc[m][n][3]);
          *reinterpret_cast<ushort4*>((unsigned short*)outB + a) = pk;
        }
      }
    }
    return;
  }

#pragma unroll
  for (int m = 0; m < 4; ++m) {
#pragma unroll
    for (int n = 0; n < 4; ++n) {
      int col = ncol0 + wc * 64 + n * 16 + l15;
#pragma unroll
      for (int r = 0; r < 4; ++r) {
        int row = mrow0 + wr * 64 + m * 16 + r0 + r;
        if (row < M) {
          float v = acc[m][n][r];
          if constexpr (EPI == 1) v *= scale;
          if constexpr (EPI == 2) {
            float xg = v + bias[col];
            v = 0.5f * xg * (1.0f + erff(xg * 0.70710678118654752f));
          }
          if constexpr (EPI == 3) {
            v += resid[(size_t)row * N + col];
            if (bias) v += bias[col];
            outF[(size_t)row * N + col] = v;
          } else {
            outB[(size_t)row * N + col] = (bf16)v;
          }
        }
      }
    }
  }
}

// ---------------- flash attention fwd v3: swizzled LDS staging + double buffer ----------------
// grid: (ceil(S/64), B*H); block 256 = 4 waves; wave w owns 16 q-rows.
// K and V^T staged via global_load_lds with PRE-SWIZZLED global source (rule #21):
// LDS dest linear; LDS slot (row, chunk c) holds global chunk c^(row&7); reads XOR back.
// Double-buffered, ONE __syncthreads per iteration (barrier drains vmcnt+lgkmcnt).
__launch_bounds__(256)
__global__ void attn_fwd3(const bf16* __restrict__ q, const bf16* __restrict__ kg,
                          const bf16* __restrict__ vt, bf16* __restrict__ cx) {
  __shared__ bf16 k_lds[2][64 * 64];
  __shared__ bf16 v_lds[2][64 * 64];
  __shared__ bf16 p_lds[4][16 * 72];

  const int t = threadIdx.x;
  const int lane = t & 63, w = t >> 6;
  const int qt = blockIdx.x;
  const int bh = blockIdx.y;
  const int l15 = lane & 15;
  const int hi = lane >> 4;
  const int khi = hi << 3;

  const size_t hoff = ((size_t)(bh >> 4) * S_) * D_ + (size_t)(bh & 15) * HD_;
  const bf16* qh = q + hoff;
  const bf16* kh = kg + hoff;
  const bf16* vh = vt + (size_t)bh * (64 * VTS_);

  // staging geometry (per thread, both tiles): row = i*32 + (t>>3), chunk = t&7
  const int st_r0 = t >> 3;          // row for i=0 (i=1 adds 32)
  const int st_c  = t & 7;           // linear dest chunk

  int qr = qt * 64 + w * 16 + l15;
  int qrc = qr < S_ ? qr : S_ - 1;
  const bf16x8 qf0 = *(const bf16x8*)(qh + (size_t)qrc * D_ + khi);
  const bf16x8 qf1 = *(const bf16x8*)(qh + (size_t)qrc * D_ + 32 + khi);

  f32x4 oacc[4] = {};
  float mrun[4], lrun[4];
#pragma unroll
  for (int r = 0; r < 4; ++r) { mrun[r] = -1e30f; lrun[r] = 0.f; }

  bf16* pw = &p_lds[w][0];
  const int NT = (S_ + 63) / 64;  // 24

  // ---- prologue: stage tile 0 into buf 0 ----
#pragma unroll
  for (int i = 0; i < 2; ++i) {
    int row = i * 32 + st_r0;
    int sc = st_c ^ (row & 7);
    int key = row;  // kt = 0
    key = key < S_ ? key : S_ - 1;
    gload16(kh + (size_t)key * D_ + sc * 8, (char*)&k_lds[0][0] + (i * 2048 + t * 8) * 2);
    gload16(vh + (size_t)row * VTS_ + sc * 8, (char*)&v_lds[0][0] + (i * 2048 + t * 8) * 2);
  }
  __syncthreads();

  int buf = 0;
  for (int kt = 0; kt < NT; ++kt) {
    // ---- stage next tile into buf^1 (in flight across this iteration) ----
    if (kt + 1 < NT) {
      int kb = (kt + 1) * 64;
#pragma unroll
      for (int i = 0; i < 2; ++i) {
        int row = i * 32 + st_r0;
        int sc = st_c ^ (row & 7);
        int key = kb + row;
        key = key < S_ ? key : S_ - 1;
        gload16(kh + (size_t)key * D_ + sc * 8,
                (char*)&k_lds[buf ^ 1][0] + (i * 2048 + t * 8) * 2);
        gload16(vh + (size_t)(kb + (sc * 8 - sc * 8)) * 0 + (size_t)row * VTS_ + kb + sc * 8,
                (char*)&v_lds[buf ^ 1][0] + (i * 2048 + t * 8) * 2);
      }
    }

    // ---- S = Q K^T from swizzled k_lds ----
    float pv[4][4];
#pragma unroll
    for (int nb = 0; nb < 4; ++nb) {
      int krow = nb * 16 + l15;
      f32x4 z = {};
      z = MFMA16(qf0, *(const bf16x8*)&k_lds[buf][krow * 64 + (((0 * 4 + hi) ^ (l15 & 7)) << 3)], z);
      z = MFMA16(qf1, *(const bf16x8*)&k_lds[buf][krow * 64 + (((1 * 4 + hi) ^ (l15 & 7)) << 3)], z);
      int key = kt * 64 + krow;
      bool cvld = key < S_;
#pragma unroll
      for (int r = 0; r < 4; ++r) pv[nb][r] = cvld ? z[r] : -1e30f;
    }

    // ---- online softmax (rows r: hi*4+r, cols: nb*16 + l15) ----
#pragma unroll
    for (int r = 0; r < 4; ++r) {
      float mx = fmaxf(fmaxf(pv[0][r], pv[1][r]), fmaxf(pv[2][r], pv[3][r]));
      mx = fmaxf(mx, __shfl_xor(mx, 1));
      mx = fmaxf(mx, __shfl_xor(mx, 2));
      mx = fmaxf(mx, __shfl_xor(mx, 4));
      mx = fmaxf(mx, __shfl_xor(mx, 8));
      float mnew = fmaxf(mrun[r], mx);
      float corr = __expf(mrun[r] - mnew);
      float ps = 0.f;
#pragma unroll
      for (int nb = 0; nb < 4; ++nb) {
        float p = __expf(pv[nb][r] - mnew);
        pv[nb][r] = p;
        ps += p;
      }
      ps += __shfl_xor(ps, 1);
      ps += __shfl_xor(ps, 2);
      ps += __shfl_xor(ps, 4);
      ps += __shfl_xor(ps, 8);
      lrun[r] = lrun[r] * corr + ps;
      mrun[r] = mnew;
#pragma unroll
      for (int db = 0; db < 4; ++db) oacc[db][r] *= corr;
    }

    // ---- P -> per-wave LDS (stride 72, XOR-swizzled chunks) ----
#pragma unroll
    for (int nb = 0; nb < 4; ++nb) {
#pragma unroll
      for (int r = 0; r < 4; ++r) {
        int prow = hi * 4 + r;
        int pcol = (nb * 16 + l15) ^ ((prow & 7) << 3);
        pw[prow * 72 + pcol] = (bf16)pv[nb][r];
      }
    }

    // ---- ctx += P @ V from swizzled v_lds ----
#pragma unroll
    for (int kk = 0; kk < 2; ++kk) {
      bf16x8 pf = *(const bf16x8*)&pw[l15 * 72 + ((kk * 32 + khi) ^ ((l15 & 7) << 3))];
#pragma unroll
      for (int db = 0; db < 4; ++db) {
        int vrow = db * 16 + l15;
        bf16x8 vf = *(const bf16x8*)&v_lds[buf][vrow * 64 + (((kk * 4 + hi) ^ (l15 & 7)) << 3)];
        oacc[db] = MFMA16(pf, vf, oacc[db]);
      }
    }

    __syncthreads();  // drains vmcnt (stage complete) + protects buffer swap
    buf ^= 1;
  }

  // ---- normalize + store ----
#pragma unroll
  for (int r = 0; r < 4; ++r) {
    int qrow = qt * 64 + w * 16 + hi * 4 + r;
    if (qrow < S_) {
      float inv = 1.0f / lrun[r];
#pragma unroll
      for (int db = 0; db < 4; ++db)
        cx[hoff + (size_t)qrow * D_ + db * 16 + l15] = (bf16)(oacc[db][r] * inv);
    }
  }
}

// ---------------- launch ----------------
extern "C" void kernel_launch(void* const* d_in, const int* in_sizes, int n_in,
                              void* d_out, int out_size, void* d_ws, size_t ws_size,
                              hipStream_t stream) {
  const float* x   = (const float*)d_in[0];
  const float* Wq  = (const float*)d_in[1];
  const float* Wk  = (const float*)d_in[2];
  const float* Wv  = (const float*)d_in[3];
  const float* Wo  = (const float*)d_in[4];
  const float* W1  = (const float*)d_in[5];
  const float* b1  = (const float*)d_in[6];
  const float* W2  = (const float*)d_in[7];
  const float* b2  = (const float*)d_in[8];
  const float* g1  = (const float*)d_in[9];
  const float* be1 = (const float*)d_in[10];
  const float* g2  = (const float*)d_in[11];
  const float* be2 = (const float*)d_in[12];
  float* out = (float*)d_out;

  char* ws = (char*)d_ws;
  bf16* wq_b  = (bf16*)(ws + WQ_OFF);
  bf16* wk_b  = (bf16*)(ws + WK_OFF);
  bf16* wv_b  = (bf16*)(ws + WV_OFF);
  bf16* wo_b  = (bf16*)(ws + WO_OFF);
  bf16* w1_b  = (bf16*)(ws + W1_OFF);
  bf16* w2_b  = (bf16*)(ws + W2_OFF);
  bf16* h_b   = (bf16*)(ws + H_OFF);
  bf16* q_b   = (bf16*)(ws + Q_OFF);
  bf16* k_b   = (bf16*)(ws + K_OFF);
  bf16* vt_b  = (bf16*)(ws + VT_OFF);
  float* x2   = (float*)(ws + X2_OFF);
  bf16* h2_b  = (bf16*)(ws + H2_OFF);
  bf16* act_b = (bf16*)(ws + ACT_OFF);
  bf16* ctx_b = h_b;  // ctx overlays h

  // weight converts
  cvt_bf16<<<(D_ * D_) / 1024, 256, 0, stream>>>(Wq, wq_b, D_ * D_);
  cvt_bf16<<<(D_ * D_) / 1024, 256, 0, stream>>>(Wk, wk_b, D_ * D_);
  cvt_bf16<<<(D_ * D_) / 1024, 256, 0, stream>>>(Wv, wv_b, D_ * D_);
  cvt_bf16<<<(D_ * D_) / 1024, 256, 0, stream>>>(Wo, wo_b, D_ * D_);
  cvt_bf16<<<(DFF_ * D_) / 1024, 256, 0, stream>>>(W1, w1_b, DFF_ * D_);
  cvt_bf16<<<(DFF_ * D_) / 1024, 256, 0, stream>>>(W2, w2_b, DFF_ * D_);

  // LN1
  ln_fused<<<M_, 256, 0, stream>>>(x, g1, be1, h_b);

  // QKV projections (V writes transposed V^T directly)
  dim3 gqkv((M_ + 127) / 128, D_ / 128);
  gemm_bt<1><<<gqkv, 256, 0, stream>>>(h_b, wq_b, M_, D_, D_, q_b, nullptr, nullptr, nullptr, 0.125f);
  gemm_bt<0><<<gqkv, 256, 0, stream>>>(h_b, wk_b, M_, D_, D_, k_b, nullptr, nullptr, nullptr, 0.f);
  gemm_bt<4><<<gqkv, 256, 0, stream>>>(h_b, wv_b, M_, D_, D_, vt_b, nullptr, nullptr, nullptr, 0.f);

  // attention (writes ctx into h region; h dead after QKV)
  attn_fwd3<<<dim3((S_ + 63) / 64, B_ * H_), 256, 0, stream>>>(q_b, k_b, vt_b, ctx_b);

  // x2 = x + ctx @ Wo^T   (x2 overlays q+k; q/k dead)
  gemm_bt<3><<<gqkv, 256, 0, stream>>>(ctx_b, wo_b, M_, D_, D_, nullptr, x2, nullptr, x, 0.f);

  // LN2 (h2 overlays vt; vt dead)
  ln_fused<<<M_, 256, 0, stream>>>(x2, g2, be2, h2_b);

  // FFN in 5 row-chunks of 2400 (act chunk overlays h/ctx; ctx dead)
  for (int c = 0; c < 5; ++c) {
    int r0c = c * 2400;
    int nr = 2400;
    int mt = (nr + 127) / 128;
    gemm_bt<2><<<dim3(mt, DFF_ / 128), 256, 0, stream>>>(
        h2_b + (size_t)r0c * D_, w1_b, nr, DFF_, D_, act_b, nullptr, b1, nullptr, 0.f);
    gemm_bt<3><<<dim3(mt, D_ / 128), 256, 0, stream>>>(
        act_b, w2_b, nr, D_, DFF_, nullptr, out + (size_t)r0c * D_, b2,
        x2 + (size_t)r0c * D_, 0.f);
  }
}

// Round 4
// 949.530 us; speedup vs baseline: 1.7724x; 1.4851x over previous
//
#include <hip/hip_runtime.h>
#include <hip/hip_bf16.h>
#include <cstdint>
#include <cstddef>

// ---------------- problem constants ----------------
#define B_    8
#define S_    1500
#define D_    1024
#define H_    16
#define HD_   64
#define DFF_  4096
#define M_    12000   // B_*S_
#define VTS_  1536    // padded seq stride for V^T

typedef __bf16 bf16;
typedef __attribute__((ext_vector_type(8))) __bf16 bf16x8;
typedef __attribute__((ext_vector_type(4))) float f32x4;

#define MFMA16(a, b, c) __builtin_amdgcn_mfma_f32_16x16x32_bf16((a), (b), (c), 0, 0, 0)

#define BAR()   do { __builtin_amdgcn_s_barrier(); __builtin_amdgcn_sched_barrier(0); } while (0)
#define LGKM0() do { asm volatile("s_waitcnt lgkmcnt(0)" ::: "memory"); __builtin_amdgcn_sched_barrier(0); } while (0)

// async global->LDS, 16B per lane (wave-uniform base + lane*16 dest).
static __device__ __forceinline__ void gload16(const void* g, void* l) {
  __builtin_amdgcn_global_load_lds(
      (const __attribute__((address_space(1))) void*)(uintptr_t)g,
      (__attribute__((address_space(3))) void*)(uintptr_t)l, 16, 0, 0);
}

static __device__ __forceinline__ unsigned short f2bu(float v) {
  bf16 h = (bf16)v;
  union { bf16 h; unsigned short u; } c;
  c.h = h;
  return c.u;
}

// ---------------- workspace layout (bytes) ----------------
// [H 24.576M][wq wk wv wo 8.39M][Q 24.576M][K 24.576M][VT 25.166M][w1 8.39M][w2 8.39M]
// overlays: x2(fp32) = Q+K; h2 = VT; act chunk (<=4000 rows) = H + wq..wo (dead after Wo GEMM)
static constexpr size_t HSZ     = (size_t)M_ * D_ * 2;              // 24,576,000
static constexpr size_t H_OFF   = 0;
static constexpr size_t WQ_OFF  = H_OFF + HSZ;
static constexpr size_t WK_OFF  = WQ_OFF + (size_t)D_ * D_ * 2;
static constexpr size_t WV_OFF  = WK_OFF + (size_t)D_ * D_ * 2;
static constexpr size_t WO_OFF  = WV_OFF + (size_t)D_ * D_ * 2;
static constexpr size_t Q_OFF   = WO_OFF + (size_t)D_ * D_ * 2;     // 32,964,608
static constexpr size_t K_OFF   = Q_OFF + HSZ;
static constexpr size_t VT_OFF  = K_OFF + HSZ;                      // V^T [128][64][1536]
static constexpr size_t W1_OFF  = VT_OFF + (size_t)128 * 64 * VTS_ * 2;
static constexpr size_t W2_OFF  = W1_OFF + (size_t)DFF_ * D_ * 2;   // total 124,059,648
static constexpr size_t X2_OFF  = Q_OFF;
static constexpr size_t H2_OFF  = VT_OFF;
static constexpr size_t ACT_OFF = H_OFF;   // act chunk: 4000*4096*2 = 32,768,000 <= 32,964,608

// ---------------- fp32 -> bf16 convert ----------------
__launch_bounds__(256)
__global__ void cvt_bf16(const float* __restrict__ src, bf16* __restrict__ dst, int n) {
  int i = (blockIdx.x * 256 + threadIdx.x) * 4;
  if (i < n) {
    float4 f = *(const float4*)(src + i);
    dst[i + 0] = (bf16)f.x;
    dst[i + 1] = (bf16)f.y;
    dst[i + 2] = (bf16)f.z;
    dst[i + 3] = (bf16)f.w;
  }
}

// ---------------- fused LayerNorm (fp32 in, bf16 out), one block per row ----------------
__launch_bounds__(256)
__global__ void ln_fused(const float* __restrict__ x, const float* __restrict__ g,
                         const float* __restrict__ bb, bf16* __restrict__ out) {
  const int row = blockIdx.x;
  const int t = threadIdx.x;
  const float4 xv = *(const float4*)(x + (size_t)row * D_ + t * 4);
  float s  = xv.x + xv.y + xv.z + xv.w;
  float s2 = xv.x * xv.x + xv.y * xv.y + xv.z * xv.z + xv.w * xv.w;
#pragma unroll
  for (int m = 32; m >= 1; m >>= 1) {
    s  += __shfl_xor(s, m);
    s2 += __shfl_xor(s2, m);
  }
  __shared__ float red[8];
  const int w = t >> 6;
  if ((t & 63) == 0) { red[w] = s; red[4 + w] = s2; }
  __syncthreads();
  s  = red[0] + red[1] + red[2] + red[3];
  s2 = red[4] + red[5] + red[6] + red[7];
  const float mu  = s * (1.0f / D_);
  const float var = s2 * (1.0f / D_) - mu * mu;
  const float rs  = rsqrtf(var + 1e-5f);
  const float4 gv = *(const float4*)(g + t * 4);
  const float4 bv = *(const float4*)(bb + t * 4);
  bf16* o = out + (size_t)row * D_ + t * 4;
  o[0] = (bf16)((xv.x - mu) * rs * gv.x + bv.x);
  o[1] = (bf16)((xv.y - mu) * rs * gv.y + bv.y);
  o[2] = (bf16)((xv.z - mu) * rs * gv.z + bv.z);
  o[3] = (bf16)((xv.w - mu) * rs * gv.w + bv.w);
}

// =====================================================================================
// gemm256: C[m][n] = sum_k A[m][k] * W[n][k], 256x256 tile, BK=32, 4-buffer pipeline.
// 512 threads = 8 waves (2 M x 4 N); per wave 128x64 out = acc[8][4] f32x4.
// Counted vmcnt (never 0 mid-loop), raw s_barrier, setprio around MFMA, XOR chunk swizzle
// with pre-swizzled global source (both-sides rule). Prefetch distance = 2 K-tiles.
// EPI: 2 = bias + exact GELU -> bf16; 3 = (+bias) + resid -> fp32; 5 = fused QKV epilogue
// =====================================================================================
template <int EPI>
__launch_bounds__(512, 2)
__global__ void gemm256(const bf16* __restrict__ A, const bf16* __restrict__ Bw,
                        int M, int N, int K,
                        bf16* __restrict__ outB, float* __restrict__ outF,
                        const float* __restrict__ bias, const float* __restrict__ resid,
                        bf16* __restrict__ outQ, bf16* __restrict__ outK2,
                        bf16* __restrict__ outV) {
  __shared__ bf16 a_lds[4][256 * 32];
  __shared__ bf16 b_lds[4][256 * 32];

  const int t = threadIdx.x;
  const int lane = t & 63, wid = t >> 6;
  const int wm = wid >> 2, wn = wid & 3;
  const int l15 = lane & 15, hi = lane >> 4;
  const int mrow0 = blockIdx.x * 256;
  const int ncol0 = blockIdx.y * 256;

  // per-lane physical chunk for fragment reads (swizzle: phys = logical ^ ((row>>1)&3);
  // fragment row base is a multiple of 16, so (row>>1)&3 == (l15>>1)&3)
  const int pc = hi ^ ((l15 >> 1) & 3);

  // staging: slot s = j*512 + t; row = s>>2, chunk c = s&3; source chunk = c ^ ((row>>1)&3)
  const int s0 = t, s1 = 512 + t;
  const int ar0 = s0 >> 2, ar1 = s1 >> 2;
  const int ac0 = ((s0 & 3) ^ ((ar0 >> 1) & 3)) * 8;
  const int ac1 = ((s1 & 3) ^ ((ar1 >> 1) & 3)) * 8;
  int ga0 = mrow0 + ar0; ga0 = ga0 < M ? ga0 : M - 1;
  int ga1 = mrow0 + ar1; ga1 = ga1 < M ? ga1 : M - 1;
  const bf16* a0 = A + (size_t)ga0 * K + ac0;
  const bf16* a1 = A + (size_t)ga1 * K + ac1;
  const bf16* b0 = Bw + (size_t)(ncol0 + ar0) * K + ac0;
  const bf16* b1 = Bw + (size_t)(ncol0 + ar1) * K + ac1;

  f32x4 acc[8][4] = {};

  const int NT = K >> 5;  // K-tiles of 32 (K is a multiple of 64)

  // ---- prologue: stage tiles 0 -> buf0, 1 -> buf1 ----
  gload16(a0,      (char*)&a_lds[0][0] + s0 * 16);
  gload16(a1,      (char*)&a_lds[0][0] + s1 * 16);
  gload16(b0,      (char*)&b_lds[0][0] + s0 * 16);
  gload16(b1,      (char*)&b_lds[0][0] + s1 * 16);
  gload16(a0 + 32, (char*)&a_lds[1][0] + s0 * 16);
  gload16(a1 + 32, (char*)&a_lds[1][0] + s1 * 16);
  gload16(b0 + 32, (char*)&b_lds[1][0] + s0 * 16);
  gload16(b1 + 32, (char*)&b_lds[1][0] + s1 * 16);
  asm volatile("s_waitcnt vmcnt(4)" ::: "memory");  // tile 0 resident
  BAR();

  int buf = 0;
  for (int tt = 0; tt < NT; ++tt) {
    const bf16* al = &a_lds[buf][0];
    const bf16* bl = &b_lds[buf][0];
    const bool do_stage = (tt + 2) < NT;
    const int nb = (tt + 2) & 3;
    const int k2 = (tt + 2) << 5;

    // ---------------- phase 0: B n0..3, A m0..3 ----------------
    if (do_stage) {
      gload16(a0 + k2, (char*)&a_lds[nb][0] + s0 * 16);
      gload16(a1 + k2, (char*)&a_lds[nb][0] + s1 * 16);
    }
    bf16x8 bf_[4], af_[4];
#pragma unroll
    for (int n = 0; n < 4; ++n)
      bf_[n] = *(const bf16x8*)&bl[(wn * 64 + n * 16 + l15) * 32 + pc * 8];
#pragma unroll
    for (int m = 0; m < 4; ++m)
      af_[m] = *(const bf16x8*)&al[(wm * 128 + m * 16 + l15) * 32 + pc * 8];
    BAR();
    LGKM0();
    __builtin_amdgcn_s_setprio(1);
#pragma unroll
    for (int m = 0; m < 4; ++m)
#pragma unroll
      for (int n = 0; n < 4; ++n)
        acc[m][n] = MFMA16(af_[m], bf_[n], acc[m][n]);
    __builtin_amdgcn_s_setprio(0);
    BAR();

    // ---------------- phase 1: A m4..7 ----------------
    if (do_stage) {
      gload16(b0 + k2, (char*)&b_lds[nb][0] + s0 * 16);
      gload16(b1 + k2, (char*)&b_lds[nb][0] + s1 * 16);
    }
#pragma unroll
    for (int m = 0; m < 4; ++m)
      af_[m] = *(const bf16x8*)&al[(wm * 128 + (m + 4) * 16 + l15) * 32 + pc * 8];
    BAR();
    LGKM0();
    __builtin_amdgcn_s_setprio(1);
#pragma unroll
    for (int m = 0; m < 4; ++m)
#pragma unroll
      for (int n = 0; n < 4; ++n)
        acc[m + 4][n] = MFMA16(af_[m], bf_[n], acc[m + 4][n]);
    __builtin_amdgcn_s_setprio(0);
    if (do_stage) asm volatile("s_waitcnt vmcnt(4)" ::: "memory");
    else          asm volatile("s_waitcnt vmcnt(0)" ::: "memory");
    BAR();
    buf = (buf + 1) & 3;
  }

  // ---------------- epilogue ----------------
  const int r0 = hi * 4;

  if constexpr (EPI == 5) {
    // fused QKV: N-tiles 0-3 = Q (scale 0.125), 4-7 = K, 8-11 = V (transposed store)
    const int mm = blockIdx.y >> 2;
    const int nloc0 = (blockIdx.y & 3) * 256;
    if (mm == 2) {
#pragma unroll
      for (int m = 0; m < 8; ++m) {
        int row0 = mrow0 + wm * 128 + m * 16 + r0;
        if (row0 < M) {
          int bb2 = row0 / 1500;
          int s = row0 - bb2 * 1500;
#pragma unroll
          for (int n = 0; n < 4; ++n) {
            int f = nloc0 + wn * 64 + n * 16 + l15;
            size_t a = ((size_t)(bb2 * 16 + (f >> 6)) * 64 + (f & 63)) * VTS_ + s;
            ushort4 pk;
            pk.x = f2bu(acc[m][n][0]);
            pk.y = f2bu(acc[m][n][1]);
            pk.z = f2bu(acc[m][n][2]);
            pk.w = f2bu(acc[m][n][3]);
            *reinterpret_cast<ushort4*>((unsigned short*)outV + a) = pk;
          }
        }
      }
    } else {
      bf16* dst = (mm == 0) ? outQ : outK2;
      const float sc = (mm == 0) ? 0.125f : 1.0f;
#pragma unroll
      for (int m = 0; m < 8; ++m) {
#pragma unroll
        for (int n = 0; n < 4; ++n) {
          int col = nloc0 + wn * 64 + n * 16 + l15;
#pragma unroll
          for (int r = 0; r < 4; ++r) {
            int row = mrow0 + wm * 128 + m * 16 + r0 + r;
            if (row < M) dst[(size_t)row * D_ + col] = (bf16)(acc[m][n][r] * sc);
          }
        }
      }
    }
    return;
  }

#pragma unroll
  for (int m = 0; m < 8; ++m) {
#pragma unroll
    for (int n = 0; n < 4; ++n) {
      int col = ncol0 + wn * 64 + n * 16 + l15;
#pragma unroll
      for (int r = 0; r < 4; ++r) {
        int row = mrow0 + wm * 128 + m * 16 + r0 + r;
        if (row < M) {
          float v = acc[m][n][r];
          if constexpr (EPI == 2) {
            float xg = v + bias[col];
            v = 0.5f * xg * (1.0f + erff(xg * 0.70710678118654752f));
            outB[(size_t)row * N + col] = (bf16)v;
          }
          if constexpr (EPI == 3) {
            v += resid[(size_t)row * N + col];
            if (bias) v += bias[col];
            outF[(size_t)row * N + col] = v;
          }
        }
      }
    }
  }
}

// ---------------- legacy 128x128 GEMM (m97 structure) — used for FFN2 (N=1024, K=4096) ----
template <int EPI>
__launch_bounds__(256)
__global__ void gemm_bt(const bf16* __restrict__ A, const bf16* __restrict__ Bw,
                        int M, int N, int K,
                        bf16* __restrict__ outB, float* __restrict__ outF,
                        const float* __restrict__ bias, const float* __restrict__ resid,
                        float scale) {
  __shared__ bf16 a_lds[128 * 64];
  __shared__ bf16 b_lds[128 * 64];
  const int t = threadIdx.x;
  const int lane = t & 63, wid = t >> 6;
  const int wr = wid >> 1, wc = wid & 1;
  const int mrow0 = blockIdx.x * 128;
  const int ncol0 = blockIdx.y * 128;
  const int l15 = lane & 15;
  const int khi = (lane >> 4) << 3;

  f32x4 acc[4][4] = {};

  for (int k0 = 0; k0 < K; k0 += 64) {
#pragma unroll
    for (int i = 0; i < 4; ++i) {
      int idx = i * 2048 + t * 8;
      int row = idx >> 6, col = idx & 63;
      int gr = mrow0 + row;
      gr = gr < M ? gr : M - 1;
      gload16(A + (size_t)gr * K + (k0 + col), (char*)a_lds + idx * 2);
    }
#pragma unroll
    for (int i = 0; i < 4; ++i) {
      int idx = i * 2048 + t * 8;
      int row = idx >> 6, col = idx & 63;
      gload16(Bw + (size_t)(ncol0 + row) * K + (k0 + col), (char*)b_lds + idx * 2);
    }
    __syncthreads();
#pragma unroll
    for (int kk = 0; kk < 2; ++kk) {
      bf16x8 af[4], bfv[4];
#pragma unroll
      for (int m = 0; m < 4; ++m)
        af[m] = *(const bf16x8*)&a_lds[(wr * 64 + m * 16 + l15) * 64 + kk * 32 + khi];
#pragma unroll
      for (int n = 0; n < 4; ++n)
        bfv[n] = *(const bf16x8*)&b_lds[(wc * 64 + n * 16 + l15) * 64 + kk * 32 + khi];
#pragma unroll
      for (int m = 0; m < 4; ++m)
#pragma unroll
        for (int n = 0; n < 4; ++n)
          acc[m][n] = MFMA16(af[m], bfv[n], acc[m][n]);
    }
    __syncthreads();
  }

  const int r0 = (lane >> 4) << 2;
#pragma unroll
  for (int m = 0; m < 4; ++m) {
#pragma unroll
    for (int n = 0; n < 4; ++n) {
      int col = ncol0 + wc * 64 + n * 16 + l15;
#pragma unroll
      for (int r = 0; r < 4; ++r) {
        int row = mrow0 + wr * 64 + m * 16 + r0 + r;
        if (row < M) {
          float v = acc[m][n][r];
          if constexpr (EPI == 2) {
            float xg = v + bias[col];
            v = 0.5f * xg * (1.0f + erff(xg * 0.70710678118654752f));
          }
          if constexpr (EPI == 3) {
            v += resid[(size_t)row * N + col];
            if (bias) v += bias[col];
            outF[(size_t)row * N + col] = v;
          } else {
            outB[(size_t)row * N + col] = (bf16)v;
          }
        }
      }
    }
  }
}

// ---------------- flash attention fwd v3 (unchanged from round 3) ----------------
__launch_bounds__(256)
__global__ void attn_fwd3(const bf16* __restrict__ q, const bf16* __restrict__ kg,
                          const bf16* __restrict__ vt, bf16* __restrict__ cx) {
  __shared__ bf16 k_lds[2][64 * 64];
  __shared__ bf16 v_lds[2][64 * 64];
  __shared__ bf16 p_lds[4][16 * 72];

  const int t = threadIdx.x;
  const int lane = t & 63, w = t >> 6;
  const int qt = blockIdx.x;
  const int bh = blockIdx.y;
  const int l15 = lane & 15;
  const int hi = lane >> 4;
  const int khi = hi << 3;

  const size_t hoff = ((size_t)(bh >> 4) * S_) * D_ + (size_t)(bh & 15) * HD_;
  const bf16* qh = q + hoff;
  const bf16* kh = kg + hoff;
  const bf16* vh = vt + (size_t)bh * (64 * VTS_);

  const int st_r0 = t >> 3;
  const int st_c  = t & 7;

  int qr = qt * 64 + w * 16 + l15;
  int qrc = qr < S_ ? qr : S_ - 1;
  const bf16x8 qf0 = *(const bf16x8*)(qh + (size_t)qrc * D_ + khi);
  const bf16x8 qf1 = *(const bf16x8*)(qh + (size_t)qrc * D_ + 32 + khi);

  f32x4 oacc[4] = {};
  float mrun[4], lrun[4];
#pragma unroll
  for (int r = 0; r < 4; ++r) { mrun[r] = -1e30f; lrun[r] = 0.f; }

  bf16* pw = &p_lds[w][0];
  const int NT = (S_ + 63) / 64;  // 24

#pragma unroll
  for (int i = 0; i < 2; ++i) {
    int row = i * 32 + st_r0;
    int sc = st_c ^ (row & 7);
    int key = row;
    key = key < S_ ? key : S_ - 1;
    gload16(kh + (size_t)key * D_ + sc * 8, (char*)&k_lds[0][0] + (i * 2048 + t * 8) * 2);
    gload16(vh + (size_t)row * VTS_ + sc * 8, (char*)&v_lds[0][0] + (i * 2048 + t * 8) * 2);
  }
  __syncthreads();

  int buf = 0;
  for (int kt = 0; kt < NT; ++kt) {
    if (kt + 1 < NT) {
      int kb = (kt + 1) * 64;
#pragma unroll
      for (int i = 0; i < 2; ++i) {
        int row = i * 32 + st_r0;
        int sc = st_c ^ (row & 7);
        int key = kb + row;
        key = key < S_ ? key : S_ - 1;
        gload16(kh + (size_t)key * D_ + sc * 8,
                (char*)&k_lds[buf ^ 1][0] + (i * 2048 + t * 8) * 2);
        gload16(vh + (size_t)row * VTS_ + kb + sc * 8,
                (char*)&v_lds[buf ^ 1][0] + (i * 2048 + t * 8) * 2);
      }
    }

    float pv[4][4];
#pragma unroll
    for (int nb = 0; nb < 4; ++nb) {
      int krow = nb * 16 + l15;
      f32x4 z = {};
      z = MFMA16(qf0, *(const bf16x8*)&k_lds[buf][krow * 64 + (((0 * 4 + hi) ^ (l15 & 7)) << 3)], z);
      z = MFMA16(qf1, *(const bf16x8*)&k_lds[buf][krow * 64 + (((1 * 4 + hi) ^ (l15 & 7)) << 3)], z);
      int key = kt * 64 + krow;
      bool cvld = key < S_;
#pragma unroll
      for (int r = 0; r < 4; ++r) pv[nb][r] = cvld ? z[r] : -1e30f;
    }

#pragma unroll
    for (int r = 0; r < 4; ++r) {
      float mx = fmaxf(fmaxf(pv[0][r], pv[1][r]), fmaxf(pv[2][r], pv[3][r]));
      mx = fmaxf(mx, __shfl_xor(mx, 1));
      mx = fmaxf(mx, __shfl_xor(mx, 2));
      mx = fmaxf(mx, __shfl_xor(mx, 4));
      mx = fmaxf(mx, __shfl_xor(mx, 8));
      float mnew = fmaxf(mrun[r], mx);
      float corr = __expf(mrun[r] - mnew);
      float ps = 0.f;
#pragma unroll
      for (int nb = 0; nb < 4; ++nb) {
        float p = __expf(pv[nb][r] - mnew);
        pv[nb][r] = p;
        ps += p;
      }
      ps += __shfl_xor(ps, 1);
      ps += __shfl_xor(ps, 2);
      ps += __shfl_xor(ps, 4);
      ps += __shfl_xor(ps, 8);
      lrun[r] = lrun[r] * corr + ps;
      mrun[r] = mnew;
#pragma unroll
      for (int db = 0; db < 4; ++db) oacc[db][r] *= corr;
    }

#pragma unroll
    for (int nb = 0; nb < 4; ++nb) {
#pragma unroll
      for (int r = 0; r < 4; ++r) {
        int prow = hi * 4 + r;
        int pcol = (nb * 16 + l15) ^ ((prow & 7) << 3);
        pw[prow * 72 + pcol] = (bf16)pv[nb][r];
      }
    }

#pragma unroll
    for (int kk = 0; kk < 2; ++kk) {
      bf16x8 pf = *(const bf16x8*)&pw[l15 * 72 + ((kk * 32 + khi) ^ ((l15 & 7) << 3))];
#pragma unroll
      for (int db = 0; db < 4; ++db) {
        int vrow = db * 16 + l15;
        bf16x8 vf = *(const bf16x8*)&v_lds[buf][vrow * 64 + (((kk * 4 + hi) ^ (l15 & 7)) << 3)];
        oacc[db] = MFMA16(pf, vf, oacc[db]);
      }
    }

    __syncthreads();
    buf ^= 1;
  }

#pragma unroll
  for (int r = 0; r < 4; ++r) {
    int qrow = qt * 64 + w * 16 + hi * 4 + r;
    if (qrow < S_) {
      float inv = 1.0f / lrun[r];
#pragma unroll
      for (int db = 0; db < 4; ++db)
        cx[hoff + (size_t)qrow * D_ + db * 16 + l15] = (bf16)(oacc[db][r] * inv);
    }
  }
}

// ---------------- launch ----------------
extern "C" void kernel_launch(void* const* d_in, const int* in_sizes, int n_in,
                              void* d_out, int out_size, void* d_ws, size_t ws_size,
                              hipStream_t stream) {
  const float* x   = (const float*)d_in[0];
  const float* Wq  = (const float*)d_in[1];
  const float* Wk  = (const float*)d_in[2];
  const float* Wv  = (const float*)d_in[3];
  const float* Wo  = (const float*)d_in[4];
  const float* W1  = (const float*)d_in[5];
  const float* b1  = (const float*)d_in[6];
  const float* W2  = (const float*)d_in[7];
  const float* b2  = (const float*)d_in[8];
  const float* g1  = (const float*)d_in[9];
  const float* be1 = (const float*)d_in[10];
  const float* g2  = (const float*)d_in[11];
  const float* be2 = (const float*)d_in[12];
  float* out = (float*)d_out;

  char* ws = (char*)d_ws;
  bf16* h_b   = (bf16*)(ws + H_OFF);
  bf16* wq_b  = (bf16*)(ws + WQ_OFF);
  bf16* wk_b  = (bf16*)(ws + WK_OFF);
  bf16* wv_b  = (bf16*)(ws + WV_OFF);
  bf16* wo_b  = (bf16*)(ws + WO_OFF);
  bf16* w1_b  = (bf16*)(ws + W1_OFF);
  bf16* w2_b  = (bf16*)(ws + W2_OFF);
  bf16* q_b   = (bf16*)(ws + Q_OFF);
  bf16* k_b   = (bf16*)(ws + K_OFF);
  bf16* vt_b  = (bf16*)(ws + VT_OFF);
  float* x2   = (float*)(ws + X2_OFF);
  bf16* h2_b  = (bf16*)(ws + H2_OFF);
  bf16* act_b = (bf16*)(ws + ACT_OFF);
  bf16* ctx_b = h_b;  // ctx overlays h

  // weight converts
  cvt_bf16<<<(D_ * D_) / 1024, 256, 0, stream>>>(Wq, wq_b, D_ * D_);
  cvt_bf16<<<(D_ * D_) / 1024, 256, 0, stream>>>(Wk, wk_b, D_ * D_);
  cvt_bf16<<<(D_ * D_) / 1024, 256, 0, stream>>>(Wv, wv_b, D_ * D_);
  cvt_bf16<<<(D_ * D_) / 1024, 256, 0, stream>>>(Wo, wo_b, D_ * D_);
  cvt_bf16<<<(DFF_ * D_) / 1024, 256, 0, stream>>>(W1, w1_b, DFF_ * D_);
  cvt_bf16<<<(DFF_ * D_) / 1024, 256, 0, stream>>>(W2, w2_b, DFF_ * D_);

  // LN1
  ln_fused<<<M_, 256, 0, stream>>>(x, g1, be1, h_b);

  // fused QKV projection: W = [wq;wk;wv] contiguous, N = 3072
  gemm256<5><<<dim3((M_ + 255) / 256, 12), 512, 0, stream>>>(
      h_b, wq_b, M_, 3072, D_, nullptr, nullptr, nullptr, nullptr, q_b, k_b, vt_b);

  // attention (writes ctx into h region; h dead after QKV)
  attn_fwd3<<<dim3((S_ + 63) / 64, B_ * H_), 256, 0, stream>>>(q_b, k_b, vt_b, ctx_b);

  // x2 = x + ctx @ Wo^T
  gemm256<3><<<dim3((M_ + 255) / 256, 4), 512, 0, stream>>>(
      ctx_b, wo_b, M_, D_, D_, nullptr, x2, nullptr, x, nullptr, nullptr, nullptr);

  // LN2 (h2 overlays vt)
  ln_fused<<<M_, 256, 0, stream>>>(x2, g2, be2, h2_b);

  // FFN in 3 row-chunks of 4000 (act overlays h + qkv/o weights, both dead)
  for (int c = 0; c < 3; ++c) {
    int r0c = c * 4000;
    int nr = 4000;
    gemm256<2><<<dim3((nr + 255) / 256, DFF_ / 256), 512, 0, stream>>>(
        h2_b + (size_t)r0c * D_, w1_b, nr, DFF_, D_, act_b, nullptr, b1, nullptr,
        nullptr, nullptr, nullptr);
    gemm_bt<3><<<dim3((nr + 127) / 128, D_ / 128), 256, 0, stream>>>(
        act_b, w2_b, nr, D_, DFF_, nullptr, out + (size_t)r0c * D_, b2,
        x2 + (size_t)r0c * D_, 0.f);
  }
}

// Round 5
// 817.607 us; speedup vs baseline: 2.0584x; 1.1614x over previous
//
#include <hip/hip_runtime.h>
#include <hip/hip_bf16.h>
#include <cstdint>
#include <cstddef>

// ---------------- problem constants ----------------
#define B_    8
#define S_    1500
#define D_    1024
#define H_    16
#define HD_   64
#define DFF_  4096
#define M_    12000   // B_*S_
#define VTS_  1536    // padded seq stride for V^T

typedef __bf16 bf16;
typedef __attribute__((ext_vector_type(8))) __bf16 bf16x8;
typedef __attribute__((ext_vector_type(4))) float f32x4;

#define MFMA16(a, b, c) __builtin_amdgcn_mfma_f32_16x16x32_bf16((a), (b), (c), 0, 0, 0)

#define BAR()   do { __builtin_amdgcn_s_barrier(); __builtin_amdgcn_sched_barrier(0); } while (0)
#define LGKM0() do { asm volatile("s_waitcnt lgkmcnt(0)" ::: "memory"); __builtin_amdgcn_sched_barrier(0); } while (0)

// async global->LDS, 16B per lane (wave-uniform base + lane*16 dest).
static __device__ __forceinline__ void gload16(const void* g, void* l) {
  __builtin_amdgcn_global_load_lds(
      (const __attribute__((address_space(1))) void*)(uintptr_t)g,
      (__attribute__((address_space(3))) void*)(uintptr_t)l, 16, 0, 0);
}

static __device__ __forceinline__ unsigned short f2bu(float v) {
  bf16 h = (bf16)v;
  union { bf16 h; unsigned short u; } c;
  c.h = h;
  return c.u;
}

// ---------------- workspace layout (bytes) ----------------
// [H][wq wk wv wo][Q][K][VT][w1][w2]  (x2/residual now lives in d_out)
// big-ws path: act full-M at 0 (over dead h..vt), h2 after w2 (total 148.6MB)
// fallback:    act chunk 4000 rows at 0 (over dead h+weights), h2 over vt
static constexpr size_t HSZ      = (size_t)M_ * D_ * 2;             // 24,576,000
static constexpr size_t H_OFF    = 0;
static constexpr size_t WQ_OFF   = H_OFF + HSZ;                     // 24,576,000
static constexpr size_t WK_OFF   = WQ_OFF + (size_t)D_ * D_ * 2;
static constexpr size_t WV_OFF   = WK_OFF + (size_t)D_ * D_ * 2;
static constexpr size_t WO_OFF   = WV_OFF + (size_t)D_ * D_ * 2;
static constexpr size_t Q_OFF    = WO_OFF + (size_t)D_ * D_ * 2;    // 32,964,608
static constexpr size_t K_OFF    = Q_OFF + HSZ;                     // 57,540,608
static constexpr size_t VT_OFF   = K_OFF + HSZ;                     // 82,116,608
static constexpr size_t W1_OFF   = VT_OFF + (size_t)128 * 64 * VTS_ * 2;  // 107,282,432
static constexpr size_t W2_OFF   = W1_OFF + (size_t)DFF_ * D_ * 2;  // 115,671,040
static constexpr size_t WS_BASE  = W2_OFF + (size_t)DFF_ * D_ * 2;  // 124,059,648
static constexpr size_t H2B_OFF  = WS_BASE;                         // big path h2
static constexpr size_t NEED_BIG = WS_BASE + HSZ;                   // 148,635,648
static constexpr size_t H2F_OFF  = VT_OFF;                          // fallback h2
static constexpr size_t ACT_OFF  = 0;                               // both paths

// ---------------- fp32 -> bf16 convert ----------------
__launch_bounds__(256)
__global__ void cvt_bf16(const float* __restrict__ src, bf16* __restrict__ dst, int n) {
  int i = (blockIdx.x * 256 + threadIdx.x) * 4;
  if (i < n) {
    float4 f = *(const float4*)(src + i);
    dst[i + 0] = (bf16)f.x;
    dst[i + 1] = (bf16)f.y;
    dst[i + 2] = (bf16)f.z;
    dst[i + 3] = (bf16)f.w;
  }
}

// ---------------- fused LayerNorm (fp32 in, bf16 out), one block per row ----------------
__launch_bounds__(256)
__global__ void ln_fused(const float* __restrict__ x, const float* __restrict__ g,
                         const float* __restrict__ bb, bf16* __restrict__ out) {
  const int row = blockIdx.x;
  const int t = threadIdx.x;
  const float4 xv = *(const float4*)(x + (size_t)row * D_ + t * 4);
  float s  = xv.x + xv.y + xv.z + xv.w;
  float s2 = xv.x * xv.x + xv.y * xv.y + xv.z * xv.z + xv.w * xv.w;
#pragma unroll
  for (int m = 32; m >= 1; m >>= 1) {
    s  += __shfl_xor(s, m);
    s2 += __shfl_xor(s2, m);
  }
  __shared__ float red[8];
  const int w = t >> 6;
  if ((t & 63) == 0) { red[w] = s; red[4 + w] = s2; }
  __syncthreads();
  s  = red[0] + red[1] + red[2] + red[3];
  s2 = red[4] + red[5] + red[6] + red[7];
  const float mu  = s * (1.0f / D_);
  const float var = s2 * (1.0f / D_) - mu * mu;
  const float rs  = rsqrtf(var + 1e-5f);
  const float4 gv = *(const float4*)(g + t * 4);
  const float4 bv = *(const float4*)(bb + t * 4);
  bf16* o = out + (size_t)row * D_ + t * 4;
  o[0] = (bf16)((xv.x - mu) * rs * gv.x + bv.x);
  o[1] = (bf16)((xv.y - mu) * rs * gv.y + bv.y);
  o[2] = (bf16)((xv.z - mu) * rs * gv.z + bv.z);
  o[3] = (bf16)((xv.w - mu) * rs * gv.w + bv.w);
}

// =====================================================================================
// gemm256: C[m][n] = sum_k A[m][k] * W[n][k], 256x256 tile, BK=32, 4-buffer pipeline.
// 512 threads = 8 waves (2 M x 4 N); per wave 128x64 out = acc[8][4] f32x4.
// Counted vmcnt (never 0 mid-loop), raw s_barrier, setprio around MFMA, XOR chunk swizzle
// with pre-swizzled global source (both-sides rule). Prefetch distance = 2 K-tiles.
// EPI: 2 = bias + exact GELU -> bf16; 3 = (+bias) + resid -> fp32 (resid may alias outF);
//      5 = fused QKV epilogue
// =====================================================================================
template <int EPI>
__launch_bounds__(512, 2)
__global__ void gemm256(const bf16* __restrict__ A, const bf16* __restrict__ Bw,
                        int M, int N, int K,
                        bf16* __restrict__ outB, float* outF,
                        const float* __restrict__ bias, const float* resid,
                        bf16* __restrict__ outQ, bf16* __restrict__ outK2,
                        bf16* __restrict__ outV) {
  __shared__ bf16 a_lds[4][256 * 32];
  __shared__ bf16 b_lds[4][256 * 32];

  const int t = threadIdx.x;
  const int lane = t & 63, wid = t >> 6;
  const int wm = wid >> 2, wn = wid & 3;
  const int l15 = lane & 15, hi = lane >> 4;
  const int mrow0 = blockIdx.x * 256;
  const int ncol0 = blockIdx.y * 256;

  // per-lane physical chunk for fragment reads (swizzle: phys = logical ^ ((row>>1)&3))
  const int pc = hi ^ ((l15 >> 1) & 3);

  // staging: slot s = j*512 + t; row = s>>2, chunk c = s&3; source chunk = c ^ ((row>>1)&3)
  const int s0 = t, s1 = 512 + t;
  const int ar0 = s0 >> 2, ar1 = s1 >> 2;
  const int ac0 = ((s0 & 3) ^ ((ar0 >> 1) & 3)) * 8;
  const int ac1 = ((s1 & 3) ^ ((ar1 >> 1) & 3)) * 8;
  int ga0 = mrow0 + ar0; ga0 = ga0 < M ? ga0 : M - 1;
  int ga1 = mrow0 + ar1; ga1 = ga1 < M ? ga1 : M - 1;
  const bf16* a0 = A + (size_t)ga0 * K + ac0;
  const bf16* a1 = A + (size_t)ga1 * K + ac1;
  const bf16* b0 = Bw + (size_t)(ncol0 + ar0) * K + ac0;
  const bf16* b1 = Bw + (size_t)(ncol0 + ar1) * K + ac1;

  f32x4 acc[8][4] = {};

  const int NT = K >> 5;  // K-tiles of 32

  // ---- prologue: stage tiles 0 -> buf0, 1 -> buf1 ----
  gload16(a0,      (char*)&a_lds[0][0] + s0 * 16);
  gload16(a1,      (char*)&a_lds[0][0] + s1 * 16);
  gload16(b0,      (char*)&b_lds[0][0] + s0 * 16);
  gload16(b1,      (char*)&b_lds[0][0] + s1 * 16);
  gload16(a0 + 32, (char*)&a_lds[1][0] + s0 * 16);
  gload16(a1 + 32, (char*)&a_lds[1][0] + s1 * 16);
  gload16(b0 + 32, (char*)&b_lds[1][0] + s0 * 16);
  gload16(b1 + 32, (char*)&b_lds[1][0] + s1 * 16);
  asm volatile("s_waitcnt vmcnt(4)" ::: "memory");  // tile 0 resident
  BAR();

  int buf = 0;
  for (int tt = 0; tt < NT; ++tt) {
    const bf16* al = &a_lds[buf][0];
    const bf16* bl = &b_lds[buf][0];
    const bool do_stage = (tt + 2) < NT;
    const int nb = (tt + 2) & 3;
    const int k2 = (tt + 2) << 5;

    // ---------------- phase 0: B n0..3, A m0..3 ----------------
    if (do_stage) {
      gload16(a0 + k2, (char*)&a_lds[nb][0] + s0 * 16);
      gload16(a1 + k2, (char*)&a_lds[nb][0] + s1 * 16);
    }
    bf16x8 bf_[4], af_[4];
#pragma unroll
    for (int n = 0; n < 4; ++n)
      bf_[n] = *(const bf16x8*)&bl[(wn * 64 + n * 16 + l15) * 32 + pc * 8];
#pragma unroll
    for (int m = 0; m < 4; ++m)
      af_[m] = *(const bf16x8*)&al[(wm * 128 + m * 16 + l15) * 32 + pc * 8];
    BAR();
    LGKM0();
    __builtin_amdgcn_s_setprio(1);
#pragma unroll
    for (int m = 0; m < 4; ++m)
#pragma unroll
      for (int n = 0; n < 4; ++n)
        acc[m][n] = MFMA16(af_[m], bf_[n], acc[m][n]);
    __builtin_amdgcn_s_setprio(0);
    BAR();

    // ---------------- phase 1: A m4..7 ----------------
    if (do_stage) {
      gload16(b0 + k2, (char*)&b_lds[nb][0] + s0 * 16);
      gload16(b1 + k2, (char*)&b_lds[nb][0] + s1 * 16);
    }
#pragma unroll
    for (int m = 0; m < 4; ++m)
      af_[m] = *(const bf16x8*)&al[(wm * 128 + (m + 4) * 16 + l15) * 32 + pc * 8];
    BAR();
    LGKM0();
    __builtin_amdgcn_s_setprio(1);
#pragma unroll
    for (int m = 0; m < 4; ++m)
#pragma unroll
      for (int n = 0; n < 4; ++n)
        acc[m + 4][n] = MFMA16(af_[m], bf_[n], acc[m + 4][n]);
    __builtin_amdgcn_s_setprio(0);
    if (do_stage) asm volatile("s_waitcnt vmcnt(4)" ::: "memory");
    else          asm volatile("s_waitcnt vmcnt(0)" ::: "memory");
    BAR();
    buf = (buf + 1) & 3;
  }

  // ---------------- epilogue ----------------
  const int r0 = hi * 4;

  if constexpr (EPI == 5) {
    // fused QKV: N-tiles 0-3 = Q (scale 0.125), 4-7 = K, 8-11 = V (transposed store)
    const int mm = blockIdx.y >> 2;
    const int nloc0 = (blockIdx.y & 3) * 256;
    if (mm == 2) {
#pragma unroll
      for (int m = 0; m < 8; ++m) {
        int row0 = mrow0 + wm * 128 + m * 16 + r0;
        if (row0 < M) {
          int bb2 = row0 / 1500;
          int s = row0 - bb2 * 1500;
#pragma unroll
          for (int n = 0; n < 4; ++n) {
            int f = nloc0 + wn * 64 + n * 16 + l15;
            size_t a = ((size_t)(bb2 * 16 + (f >> 6)) * 64 + (f & 63)) * VTS_ + s;
            ushort4 pk;
            pk.x = f2bu(acc[m][n][0]);
            pk.y = f2bu(acc[m][n][1]);
            pk.z = f2bu(acc[m][n][2]);
            pk.w = f2bu(acc[m][n][3]);
            *reinterpret_cast<ushort4*>((unsigned short*)outV + a) = pk;
          }
        }
      }
    } else {
      bf16* dst = (mm == 0) ? outQ : outK2;
      const float sc = (mm == 0) ? 0.125f : 1.0f;
#pragma unroll
      for (int m = 0; m < 8; ++m) {
#pragma unroll
        for (int n = 0; n < 4; ++n) {
          int col = nloc0 + wn * 64 + n * 16 + l15;
#pragma unroll
          for (int r = 0; r < 4; ++r) {
            int row = mrow0 + wm * 128 + m * 16 + r0 + r;
            if (row < M) dst[(size_t)row * D_ + col] = (bf16)(acc[m][n][r] * sc);
          }
        }
      }
    }
    return;
  }

#pragma unroll
  for (int m = 0; m < 8; ++m) {
#pragma unroll
    for (int n = 0; n < 4; ++n) {
      int col = ncol0 + wn * 64 + n * 16 + l15;
#pragma unroll
      for (int r = 0; r < 4; ++r) {
        int row = mrow0 + wm * 128 + m * 16 + r0 + r;
        if (row < M) {
          float v = acc[m][n][r];
          if constexpr (EPI == 2) {
            float xg = v + bias[col];
            v = 0.5f * xg * (1.0f + erff(xg * 0.70710678118654752f));
            outB[(size_t)row * N + col] = (bf16)v;
          }
          if constexpr (EPI == 3) {
            v += resid[(size_t)row * N + col];
            if (bias) v += bias[col];
            outF[(size_t)row * N + col] = v;
          }
        }
      }
    }
  }
}

// ---------------- legacy 128x128 GEMM (fallback FFN2 only) ----------------
template <int EPI>
__launch_bounds__(256)
__global__ void gemm_bt(const bf16* __restrict__ A, const bf16* __restrict__ Bw,
                        int M, int N, int K,
                        bf16* __restrict__ outB, float* outF,
                        const float* __restrict__ bias, const float* resid,
                        float scale) {
  __shared__ bf16 a_lds[128 * 64];
  __shared__ bf16 b_lds[128 * 64];
  const int t = threadIdx.x;
  const int lane = t & 63, wid = t >> 6;
  const int wr = wid >> 1, wc = wid & 1;
  const int mrow0 = blockIdx.x * 128;
  const int ncol0 = blockIdx.y * 128;
  const int l15 = lane & 15;
  const int khi = (lane >> 4) << 3;

  f32x4 acc[4][4] = {};

  for (int k0 = 0; k0 < K; k0 += 64) {
#pragma unroll
    for (int i = 0; i < 4; ++i) {
      int idx = i * 2048 + t * 8;
      int row = idx >> 6, col = idx & 63;
      int gr = mrow0 + row;
      gr = gr < M ? gr : M - 1;
      gload16(A + (size_t)gr * K + (k0 + col), (char*)a_lds + idx * 2);
    }
#pragma unroll
    for (int i = 0; i < 4; ++i) {
      int idx = i * 2048 + t * 8;
      int row = idx >> 6, col = idx & 63;
      gload16(Bw + (size_t)(ncol0 + row) * K + (k0 + col), (char*)b_lds + idx * 2);
    }
    __syncthreads();
#pragma unroll
    for (int kk = 0; kk < 2; ++kk) {
      bf16x8 af[4], bfv[4];
#pragma unroll
      for (int m = 0; m < 4; ++m)
        af[m] = *(const bf16x8*)&a_lds[(wr * 64 + m * 16 + l15) * 64 + kk * 32 + khi];
#pragma unroll
      for (int n = 0; n < 4; ++n)
        bfv[n] = *(const bf16x8*)&b_lds[(wc * 64 + n * 16 + l15) * 64 + kk * 32 + khi];
#pragma unroll
      for (int m = 0; m < 4; ++m)
#pragma unroll
        for (int n = 0; n < 4; ++n)
          acc[m][n] = MFMA16(af[m], bfv[n], acc[m][n]);
    }
    __syncthreads();
  }

  const int r0 = (lane >> 4) << 2;
#pragma unroll
  for (int m = 0; m < 4; ++m) {
#pragma unroll
    for (int n = 0; n < 4; ++n) {
      int col = ncol0 + wc * 64 + n * 16 + l15;
#pragma unroll
      for (int r = 0; r < 4; ++r) {
        int row = mrow0 + wr * 64 + m * 16 + r0 + r;
        if (row < M) {
          float v = acc[m][n][r];
          if constexpr (EPI == 2) {
            float xg = v + bias[col];
            v = 0.5f * xg * (1.0f + erff(xg * 0.70710678118654752f));
          }
          if constexpr (EPI == 3) {
            v += resid[(size_t)row * N + col];
            if (bias) v += bias[col];
            outF[(size_t)row * N + col] = v;
          } else {
            outB[(size_t)row * N + col] = (bf16)v;
          }
        }
      }
    }
  }
}

// ---------------- flash attention fwd v3 + defer-max (T13) ----------------
__launch_bounds__(256)
__global__ void attn_fwd3(const bf16* __restrict__ q, const bf16* __restrict__ kg,
                          const bf16* __restrict__ vt, bf16* __restrict__ cx) {
  __shared__ bf16 k_lds[2][64 * 64];
  __shared__ bf16 v_lds[2][64 * 64];
  __shared__ bf16 p_lds[4][16 * 72];

  const int t = threadIdx.x;
  const int lane = t & 63, w = t >> 6;
  const int qt = blockIdx.x;
  const int bh = blockIdx.y;
  const int l15 = lane & 15;
  const int hi = lane >> 4;
  const int khi = hi << 3;

  const size_t hoff = ((size_t)(bh >> 4) * S_) * D_ + (size_t)(bh & 15) * HD_;
  const bf16* qh = q + hoff;
  const bf16* kh = kg + hoff;
  const bf16* vh = vt + (size_t)bh * (64 * VTS_);

  const int st_r0 = t >> 3;
  const int st_c  = t & 7;

  int qr = qt * 64 + w * 16 + l15;
  int qrc = qr < S_ ? qr : S_ - 1;
  const bf16x8 qf0 = *(const bf16x8*)(qh + (size_t)qrc * D_ + khi);
  const bf16x8 qf1 = *(const bf16x8*)(qh + (size_t)qrc * D_ + 32 + khi);

  f32x4 oacc[4] = {};
  float mrun[4], lrun[4];
#pragma unroll
  for (int r = 0; r < 4; ++r) { mrun[r] = -1e30f; lrun[r] = 0.f; }

  bf16* pw = &p_lds[w][0];
  const int NT = (S_ + 63) / 64;  // 24

#pragma unroll
  for (int i = 0; i < 2; ++i) {
    int row = i * 32 + st_r0;
    int sc = st_c ^ (row & 7);
    int key = row;
    key = key < S_ ? key : S_ - 1;
    gload16(kh + (size_t)key * D_ + sc * 8, (char*)&k_lds[0][0] + (i * 2048 + t * 8) * 2);
    gload16(vh + (size_t)row * VTS_ + sc * 8, (char*)&v_lds[0][0] + (i * 2048 + t * 8) * 2);
  }
  __syncthreads();

  int buf = 0;
  for (int kt = 0; kt < NT; ++kt) {
    if (kt + 1 < NT) {
      int kb = (kt + 1) * 64;
#pragma unroll
      for (int i = 0; i < 2; ++i) {
        int row = i * 32 + st_r0;
        int sc = st_c ^ (row & 7);
        int key = kb + row;
        key = key < S_ ? key : S_ - 1;
        gload16(kh + (size_t)key * D_ + sc * 8,
                (char*)&k_lds[buf ^ 1][0] + (i * 2048 + t * 8) * 2);
        gload16(vh + (size_t)row * VTS_ + kb + sc * 8,
                (char*)&v_lds[buf ^ 1][0] + (i * 2048 + t * 8) * 2);
      }
    }

    float pv[4][4];
#pragma unroll
    for (int nb = 0; nb < 4; ++nb) {
      int krow = nb * 16 + l15;
      f32x4 z = {};
      z = MFMA16(qf0, *(const bf16x8*)&k_lds[buf][krow * 64 + (((0 * 4 + hi) ^ (l15 & 7)) << 3)], z);
      z = MFMA16(qf1, *(const bf16x8*)&k_lds[buf][krow * 64 + (((1 * 4 + hi) ^ (l15 & 7)) << 3)], z);
      int key = kt * 64 + krow;
      bool cvld = key < S_;
#pragma unroll
      for (int r = 0; r < 4; ++r) pv[nb][r] = cvld ? z[r] : -1e30f;
    }

    // ---- per-row max (wave-parallel) ----
    float mx4[4];
#pragma unroll
    for (int r = 0; r < 4; ++r) {
      float mx = fmaxf(fmaxf(pv[0][r], pv[1][r]), fmaxf(pv[2][r], pv[3][r]));
      mx = fmaxf(mx, __shfl_xor(mx, 1));
      mx = fmaxf(mx, __shfl_xor(mx, 2));
      mx = fmaxf(mx, __shfl_xor(mx, 4));
      mx = fmaxf(mx, __shfl_xor(mx, 8));
      mx4[r] = mx;
    }

    // ---- defer-max: skip rescale when growth <= 8 (P bounded by e^8) ----
    bool ok = (mx4[0] <= mrun[0] + 8.f) && (mx4[1] <= mrun[1] + 8.f) &&
              (mx4[2] <= mrun[2] + 8.f) && (mx4[3] <= mrun[3] + 8.f);
    if (!__all(ok)) {
#pragma unroll
      for (int r = 0; r < 4; ++r) {
        float mnew = fmaxf(mrun[r], mx4[r]);
        float corr = __expf(mrun[r] - mnew);
        lrun[r] *= corr;
        mrun[r] = mnew;
#pragma unroll
        for (int db = 0; db < 4; ++db) oacc[db][r] *= corr;
      }
    }

#pragma unroll
    for (int r = 0; r < 4; ++r) {
      float ps = 0.f;
#pragma unroll
      for (int nb = 0; nb < 4; ++nb) {
        float p = __expf(pv[nb][r] - mrun[r]);
        pv[nb][r] = p;
        ps += p;
      }
      ps += __shfl_xor(ps, 1);
      ps += __shfl_xor(ps, 2);
      ps += __shfl_xor(ps, 4);
      ps += __shfl_xor(ps, 8);
      lrun[r] += ps;
    }

#pragma unroll
    for (int nb = 0; nb < 4; ++nb) {
#pragma unroll
      for (int r = 0; r < 4; ++r) {
        int prow = hi * 4 + r;
        int pcol = (nb * 16 + l15) ^ ((prow & 7) << 3);
        pw[prow * 72 + pcol] = (bf16)pv[nb][r];
      }
    }

#pragma unroll
    for (int kk = 0; kk < 2; ++kk) {
      bf16x8 pf = *(const bf16x8*)&pw[l15 * 72 + ((kk * 32 + khi) ^ ((l15 & 7) << 3))];
#pragma unroll
      for (int db = 0; db < 4; ++db) {
        int vrow = db * 16 + l15;
        bf16x8 vf = *(const bf16x8*)&v_lds[buf][vrow * 64 + (((kk * 4 + hi) ^ (l15 & 7)) << 3)];
        oacc[db] = MFMA16(pf, vf, oacc[db]);
      }
    }

    __syncthreads();
    buf ^= 1;
  }

#pragma unroll
  for (int r = 0; r < 4; ++r) {
    int qrow = qt * 64 + w * 16 + hi * 4 + r;
    if (qrow < S_) {
      float inv = 1.0f / lrun[r];
#pragma unroll
      for (int db = 0; db < 4; ++db)
        cx[hoff + (size_t)qrow * D_ + db * 16 + l15] = (bf16)(oacc[db][r] * inv);
    }
  }
}

// ---------------- launch ----------------
extern "C" void kernel_launch(void* const* d_in, const int* in_sizes, int n_in,
                              void* d_out, int out_size, void* d_ws, size_t ws_size,
                              hipStream_t stream) {
  const float* x   = (const float*)d_in[0];
  const float* Wq  = (const float*)d_in[1];
  const float* Wk  = (const float*)d_in[2];
  const float* Wv  = (const float*)d_in[3];
  const float* Wo  = (const float*)d_in[4];
  const float* W1  = (const float*)d_in[5];
  const float* b1  = (const float*)d_in[6];
  const float* W2  = (const float*)d_in[7];
  const float* b2  = (const float*)d_in[8];
  const float* g1  = (const float*)d_in[9];
  const float* be1 = (const float*)d_in[10];
  const float* g2  = (const float*)d_in[11];
  const float* be2 = (const float*)d_in[12];
  float* out = (float*)d_out;

  char* ws = (char*)d_ws;
  bf16* h_b   = (bf16*)(ws + H_OFF);
  bf16* wq_b  = (bf16*)(ws + WQ_OFF);
  bf16* wk_b  = (bf16*)(ws + WK_OFF);
  bf16* wv_b  = (bf16*)(ws + WV_OFF);
  bf16* wo_b  = (bf16*)(ws + WO_OFF);
  bf16* w1_b  = (bf16*)(ws + W1_OFF);
  bf16* w2_b  = (bf16*)(ws + W2_OFF);
  bf16* q_b   = (bf16*)(ws + Q_OFF);
  bf16* k_b   = (bf16*)(ws + K_OFF);
  bf16* vt_b  = (bf16*)(ws + VT_OFF);
  bf16* act_b = (bf16*)(ws + ACT_OFF);
  bf16* ctx_b = h_b;  // ctx overlays h

  const bool big = ws_size >= NEED_BIG;
  bf16* h2_b = (bf16*)(ws + (big ? H2B_OFF : H2F_OFF));

  // weight converts
  cvt_bf16<<<(D_ * D_) / 1024, 256, 0, stream>>>(Wq, wq_b, D_ * D_);
  cvt_bf16<<<(D_ * D_) / 1024, 256, 0, stream>>>(Wk, wk_b, D_ * D_);
  cvt_bf16<<<(D_ * D_) / 1024, 256, 0, stream>>>(Wv, wv_b, D_ * D_);
  cvt_bf16<<<(D_ * D_) / 1024, 256, 0, stream>>>(Wo, wo_b, D_ * D_);
  cvt_bf16<<<(DFF_ * D_) / 1024, 256, 0, stream>>>(W1, w1_b, DFF_ * D_);
  cvt_bf16<<<(DFF_ * D_) / 1024, 256, 0, stream>>>(W2, w2_b, DFF_ * D_);

  // LN1
  ln_fused<<<M_, 256, 0, stream>>>(x, g1, be1, h_b);

  // fused QKV projection: W = [wq;wk;wv] contiguous, N = 3072
  gemm256<5><<<dim3((M_ + 255) / 256, 12), 512, 0, stream>>>(
      h_b, wq_b, M_, 3072, D_, nullptr, nullptr, nullptr, nullptr, q_b, k_b, vt_b);

  // attention (writes ctx into h region; h dead after QKV)
  attn_fwd3<<<dim3((S_ + 63) / 64, B_ * H_), 256, 0, stream>>>(q_b, k_b, vt_b, ctx_b);

  // out = x + ctx @ Wo^T   (residual lives in d_out)
  gemm256<3><<<dim3((M_ + 255) / 256, 4), 512, 0, stream>>>(
      ctx_b, wo_b, M_, D_, D_, nullptr, out, nullptr, x, nullptr, nullptr, nullptr);

  // LN2 reads d_out
  ln_fused<<<M_, 256, 0, stream>>>(out, g2, be2, h2_b);

  if (big) {
    // full-M FFN: act (98.3MB) spans dead h/weights/q/k/vt; h2 sits past w2
    gemm256<2><<<dim3((M_ + 255) / 256, DFF_ / 256), 512, 0, stream>>>(
        h2_b, w1_b, M_, DFF_, D_, act_b, nullptr, b1, nullptr,
        nullptr, nullptr, nullptr);
    gemm256<3><<<dim3((M_ + 255) / 256, D_ / 256), 512, 0, stream>>>(
        act_b, w2_b, M_, D_, DFF_, nullptr, out, b2, out,
        nullptr, nullptr, nullptr);
  } else {
    // fallback: 3 row-chunks of 4000 (act over dead h+qkv/o weights)
    for (int c = 0; c < 3; ++c) {
      int r0c = c * 4000;
      int nr = 4000;
      gemm256<2><<<dim3((nr + 255) / 256, DFF_ / 256), 512, 0, stream>>>(
          h2_b + (size_t)r0c * D_, w1_b, nr, DFF_, D_, act_b, nullptr, b1, nullptr,
          nullptr, nullptr, nullptr);
      gemm_bt<3><<<dim3((nr + 127) / 128, D_ / 128), 256, 0, stream>>>(
          act_b, w2_b, nr, D_, DFF_, nullptr, out + (size_t)r0c * D_, b2,
          out + (size_t)r0c * D_, 0.f);
    }
  }
}